// Round 4
// baseline (79.459 us; speedup 1.0000x reference)
//
#include <hip/hip_runtime.h>

#define B_SZ 8192
#define L_SZ 128
#define P_PAIRS 4096
#define NBLK_G 64                  // gram blocks; entries = rows 0..1 of gram
#define MARGIN 64.0f
#define MAGIC 0x5A5A5A5A           // != 0xAAAAAAAA ws poison

// 4-byte-word offsets into ws
#define FLAG_OFF  0                // int[384]    per-producer-block ready flag
#define CNT_OFF   384              // int[64]     per-gram-block candidate count
#define CB_OFF    448              // u64[64*4]   per-block 256-bit candmask (byte 1792, 8-aligned)
#define VSUM_OFF  960              // float[64]   per-block full candidate v^2 sum
#define POS_OFF   1024             // float[128]  per-block pos-hinge partials
#define QUANT_OFF 1152             // float[128]  per-block quant partials
#define BITS_OFF  1280             // float[64*128] bit colsums (byte 5120, 16-aligned)
#define BITS4_OFF 320              // BITS_OFF/4 as float4 index
#define GRAM_OFF  9472             // float[16384] gram rows 0..1

__global__ __launch_bounds__(256) void k_fused(const float* __restrict__ bin,
                                               const float* __restrict__ cont,
                                               const int* __restrict__ pos,
                                               void* __restrict__ wsv,
                                               float* __restrict__ out) {
    float* ws_f = (float*)wsv;
    int* ws_i = (int*)wsv;
    float4* ws_4 = (float4*)wsv;
    const int bid = blockIdx.x, tid = threadIdx.x;
    const int lane = tid & 63, wv = tid >> 6;

    if (bid < NBLK_G) {                               // ---- gram + cand/count/vsum ----
        __shared__ float rowi[L_SZ];
        __shared__ unsigned char flag[256];
        __shared__ float rsum[4];
        __shared__ int rcnt[4];
        const int b = bid;
        const int i = b >> 5;                          // row 0 or 1
        const int jbase = (b & 31) * 256;
        flag[tid] = 0;
        if (tid < L_SZ) rowi[tid] = bin[i * L_SZ + tid];
        __syncthreads();
        const int2* pp = (const int2*)pos;
#pragma unroll
        for (int r = 0; r < P_PAIRS / 256; ++r) {      // mark positives hitting my range
            int2 qd = pp[r * 256 + tid];
            if (qd.x == i) { int dj = qd.y - jbase; if ((unsigned)dj < 256u) flag[dj] = 1; }
            if (qd.y == i) { int dj = qd.x - jbase; if ((unsigned)dj < 256u) flag[dj] = 1; }
        }
        __syncthreads();
        const int j = jbase + tid;
        const float4* rj = (const float4*)(bin + (long)j * L_SZ);
        const float4* ri4 = (const float4*)rowi;
        float s = 0.f;
#pragma unroll
        for (int k = 0; k < 32; ++k) {
            float4 a = ri4[k], c = rj[k];
            s += a.x * c.x + a.y * c.y + a.z * c.z + a.w * c.w;
        }
        ws_f[GRAM_OFF + b * 256 + tid] = s;
        const bool cand = (j != i) && !flag[tid];
        unsigned long long bm = __ballot(cand);
        if (lane == 0)
            ((unsigned long long*)(ws_i + CB_OFF))[b * 4 + wv] = bm;
        float v = cand ? fmaxf(s + MARGIN, 0.f) : 0.f;
        v = v * v;
        int cnt = cand ? 1 : 0;
#pragma unroll
        for (int o = 32; o; o >>= 1) { v += __shfl_down(v, o); cnt += __shfl_down(cnt, o); }
        if (lane == 0) { rsum[wv] = v; rcnt[wv] = cnt; }
        __syncthreads();
        if (tid == 0) {
            ws_f[VSUM_OFF + b] = rsum[0] + rsum[1] + rsum[2] + rsum[3];
            ws_i[CNT_OFF + b] = rcnt[0] + rcnt[1] + rcnt[2] + rcnt[3];
        }
    } else if (bid < 192) {                           // ---- pos pairs ----
        const int sub = lane >> 4, sl = lane & 15;
        const int w = (bid - 64) * 4 + wv;            // wave id [0,512), 8 pairs each
        float contrib = 0.f;
#pragma unroll
        for (int st = 0; st < 2; ++st) {
            int p = w * 8 + st * 4 + sub;
            int q = pos[2 * p], d = pos[2 * p + 1];
            const float4* rq = (const float4*)(bin + (long)q * L_SZ);
            const float4* rd = (const float4*)(bin + (long)d * L_SZ);
            float4 a0 = rq[sl], a1 = rq[sl + 16];
            float4 b0 = rd[sl], b1 = rd[sl + 16];
            float s = a0.x * b0.x + a0.y * b0.y + a0.z * b0.z + a0.w * b0.w
                    + a1.x * b1.x + a1.y * b1.y + a1.z * b1.z + a1.w * b1.w;
            s += __shfl_down(s, 8); s += __shfl_down(s, 4);
            s += __shfl_down(s, 2); s += __shfl_down(s, 1);
            if (sl == 0) { float m = fmaxf(MARGIN - s, 0.f); contrib += m * m; }
        }
        contrib += __shfl_down(contrib, 16);
        contrib += __shfl_down(contrib, 32);
        __shared__ float pw[4];
        if (lane == 0) pw[wv] = contrib;
        __syncthreads();
        if (tid == 0) ws_f[POS_OFF + (bid - 64)] = pw[0] + pw[1] + pw[2] + pw[3];
    } else if (bid < 320) {                           // ---- quant ----
        int idx = (bid - 192) * 256 + tid;
        const float4* c4 = (const float4*)cont;
        float s = 0.f;
#pragma unroll
        for (int k = 0; k < 8; ++k) {
            float4 v = c4[idx + k * 32768];
            s += fabsf(fabsf(v.x) - 1.f) + fabsf(fabsf(v.y) - 1.f) +
                 fabsf(fabsf(v.z) - 1.f) + fabsf(fabsf(v.w) - 1.f);
        }
#pragma unroll
        for (int o = 32; o; o >>= 1) s += __shfl_down(s, o);
        __shared__ float sw[4];
        if (lane == 0) sw[wv] = s;
        __syncthreads();
        if (tid == 0) ws_f[QUANT_OFF + (bid - 192)] = sw[0] + sw[1] + sw[2] + sw[3];
    } else if (bid < 384) {                           // ---- bit colsums (float4) ----
        const int b = bid - 320;                      // 64 blocks x 128 rows
        const int cq = tid & 31, r0 = tid >> 5;       // col-quad, row-group
        const float4* b4 = (const float4*)bin;
        long base = (long)b * 128;
        float4 a = make_float4(0.f, 0.f, 0.f, 0.f);
        for (int r = r0; r < 128; r += 8) {
            float4 v = b4[(base + r) * 32 + cq];
            a.x += v.x; a.y += v.y; a.z += v.z; a.w += v.w;
        }
        __shared__ float4 s4[256];
        s4[tid] = a;
        __syncthreads();
        if (tid < 32) {
            float4 c = s4[tid];
#pragma unroll
            for (int g = 1; g < 8; ++g) {
                float4 v = s4[tid + 32 * g];
                c.x += v.x; c.y += v.y; c.z += v.z; c.w += v.w;
            }
            ws_4[BITS4_OFF + b * 32 + tid] = c;
        }
    } else {                                          // ============ FINALE ============
        // spin until all 384 producer flags set
        for (int f = tid; f < 384; f += 256)
            while (__hip_atomic_load(&ws_i[FLAG_OFF + f], __ATOMIC_RELAXED,
                                     __HIP_MEMORY_SCOPE_AGENT) != MAGIC)
                __builtin_amdgcn_s_sleep(1);
        __syncthreads();
        __builtin_amdgcn_fence(__ATOMIC_ACQUIRE, "agent");

        __shared__ int meta[2];
        __shared__ int wtot[4], woff_s[4];
        __shared__ float4 s4[256];
        __shared__ float fred[4];
        const int t = tid;

        if (wv == 0) {                                // scan 64 block counts
            int c = ws_i[CNT_OFF + lane];
            int x = c;
#pragma unroll
            for (int o = 1; o < 64; o <<= 1) {
                int y = __shfl_up(x, o);
                if (lane >= o) x += y;
            }
            if ((x - c) < P_PAIRS && x >= P_PAIRS) {  // unique crossing lane
                meta[0] = lane; meta[1] = P_PAIRS - (x - c);
            }
        }
        __syncthreads();
        const int cstar = meta[0], rem = meta[1];

        unsigned long long cw =
            ((const unsigned long long*)(ws_i + CB_OFF))[cstar * 4 + wv];
        const bool cand = (cw >> lane) & 1ull;
        unsigned long long bm = __ballot(cand);
        int rw = __popcll(bm & ((1ull << lane) - 1ull));
        if (lane == 63) wtot[wv] = __popcll(bm);
        __syncthreads();
        if (t == 0) { int s = 0; for (int w = 0; w < 4; ++w) { woff_s[w] = s; s += wtot[w]; } }
        __syncthreads();
        const int rank = woff_s[wv] + rw;

        const float inv2p = 1.0f / (float)(2 * P_PAIRS);
        float val = 0.f;
        if (cand && rank < rem) {
            float g = ws_f[GRAM_OFF + cstar * 256 + t];
            float u = fmaxf(g + MARGIN, 0.f);
            val += u * u * inv2p;
        }
        if (t < 64 && t < cstar) val += ws_f[VSUM_OFF + t] * inv2p;
        if (t < 128) {
            val += ws_f[POS_OFF + t] * inv2p;
            val += ws_f[QUANT_OFF + t] * (0.5f / (float)(B_SZ * L_SZ));
        }

        {   // bit-balance: 64 float4 partials per col-quad
            int cq = t & 31, g = t >> 5;
            float4 a = make_float4(0.f, 0.f, 0.f, 0.f);
            for (int b = g; b < 64; b += 8) {
                float4 v = ws_4[BITS4_OFF + b * 32 + cq];
                a.x += v.x; a.y += v.y; a.z += v.z; a.w += v.w;
            }
            s4[t] = a;
        }
        __syncthreads();
        if (t < 32) {
            float4 c = s4[t];
#pragma unroll
            for (int g = 1; g < 8; ++g) {
                float4 v = s4[t + 32 * g];
                c.x += v.x; c.y += v.y; c.z += v.z; c.w += v.w;
            }
            const float invb = 1.0f / (float)B_SZ;
            float mx = c.x * invb, my = c.y * invb, mz = c.z * invb, mw = c.w * invb;
            val += 0.1f * (mx * mx + my * my + mz * mz + mw * mw);
        }
        __syncthreads();
#pragma unroll
        for (int o = 32; o; o >>= 1) val += __shfl_down(val, o);
        if (lane == 0) fred[wv] = val;
        __syncthreads();
        if (t == 0) out[0] = fred[0] + fred[1] + fred[2] + fred[3];
        return;
    }

    // ---- producer epilogue: publish ready flag (device scope) ----
    __syncthreads();                                  // all block stores issued+drained
    if (tid == 0) {
        __builtin_amdgcn_fence(__ATOMIC_RELEASE, "agent");
        __hip_atomic_store(&ws_i[FLAG_OFF + bid], MAGIC, __ATOMIC_RELAXED,
                           __HIP_MEMORY_SCOPE_AGENT);
    }
}

extern "C" void kernel_launch(void* const* d_in, const int* in_sizes, int n_in,
                              void* d_out, int out_size, void* d_ws, size_t ws_size,
                              hipStream_t stream) {
    const float* bin = (const float*)d_in[0];
    const float* cont = (const float*)d_in[1];
    const int* pos = (const int*)d_in[2];
    float* out = (float*)d_out;

    k_fused<<<385, 256, 0, stream>>>(bin, cont, pos, d_ws, out);
}